// Round 9
// baseline (322.957 us; speedup 1.0000x reference)
//
#include <hip/hip_runtime.h>
#include <stdint.h>

#define M_DIM 8192
#define N_DIM 4096
#define K_DIM 4096
#define NBLK  (K_DIM / 32)

typedef __attribute__((ext_vector_type(4)))  float          f32x4;
typedef __attribute__((ext_vector_type(16))) float          f32x16;
typedef __attribute__((ext_vector_type(8)))  short          bf16x8;
typedef __attribute__((ext_vector_type(4)))  int            i32x4;
typedef __attribute__((ext_vector_type(8)))  unsigned short u16x8;
typedef __attribute__((address_space(3)))    unsigned short lds_us;

// round-to-nearest-even fp32 -> bf16 bits (finite values only)
__device__ __forceinline__ unsigned short f2bf(float f) {
  unsigned u = __builtin_bit_cast(unsigned, f);
  u += 0x7fffu + ((u >> 16) & 1u);
  return (unsigned short)(u >> 16);
}

__device__ __forceinline__ void stage16(const unsigned short* g, lds_us* l) {
  __builtin_amdgcn_global_load_lds(
      (const __attribute__((address_space(1))) void*)g,
      (__attribute__((address_space(3))) void*)l, 16, 0, 0);
}

// inline-asm ds_read_b128 with immediate byte offset
template <int OFF>
__device__ __forceinline__ bf16x8 dsr(lds_us* addr) {
  bf16x8 d;
  asm volatile("ds_read_b128 %0, %1 offset:%2" : "=v"(d) : "v"(addr), "n"(OFF));
  return d;
}

// inline-asm global_load_dwordx4 (direct-to-register B fragments)
template <int OFF>
__device__ __forceinline__ bf16x8 gld(const unsigned short* addr) {
  bf16x8 d;
  asm volatile("global_load_dwordx4 %0, %1, off offset:%2"
               : "=v"(d) : "v"(addr), "n"(OFF));
  return d;
}

// ============ BLOCKED GLOBAL LAYOUT for xb / wb (32x32x16 fragments) ======
// Granule = 16 B = one lane's MFMA frag slice (8 bf16). Granule id t:
//   lane l = t&63         -> row-in-frag r = l&31, k-chunk c' = l>>5
//   sub    = (t>>6)&15    -> m-block mb = sub>>2 (32 rows), k-step ks = sub&3
//   H      = next bits    -> 128-row half;  g = top bits -> K-tile (K=64)
// Element (row,k): row = H*128 + mb*32 + r;  k = g*64 + ks*16 + c'*8.
// (H, K-tile) block = contiguous 16 KB; within a 1-KB subtile granule slot ==
// MFMA lane. So A staging is identity-copy (conflict-free ds_read) and B
// fragments are DIRECTLY loadable global->reg, perfectly coalesced.

// ---------------- dequant: wq int32 [N,K] row-major -> wb blocked bf16
__global__ void MXFP4_dequant_kernel(const int* __restrict__ wq,
                                     const float* __restrict__ scales,
                                     unsigned short* __restrict__ wb) {
  size_t t = (size_t)blockIdx.x * 256 + threadIdx.x;   // granule id
  int l  = (int)(t & 63);
  int r  = l & 31, cq = l >> 5;
  int sub = (int)(t >> 6) & 15;
  int mb = sub >> 2, ks = sub & 3;
  int H = (int)(t >> 10) & 31;
  int g = (int)(t >> 15);
  size_t row = (size_t)H * 128 + mb * 32 + r;
  size_t k   = (size_t)g * 64 + ks * 16 + cq * 8;
  float s = scales[row * NBLK + (k >> 5)] * (1.0f / 7.0f);
  const int* src = wq + row * K_DIM + k;
  i32x4 q0 = *(const i32x4*)src;
  i32x4 q1 = *(const i32x4*)(src + 4);
  u16x8 out;
#pragma unroll
  for (int j = 0; j < 4; ++j) out[j]     = f2bf((float)q0[j] * s);
#pragma unroll
  for (int j = 0; j < 4; ++j) out[4 + j] = f2bf((float)q1[j] * s);
  *(u16x8*)(wb + t * 8) = out;
}

// ---------------- x fp32 [M,K] row-major -> xb blocked bf16
__global__ void MXFP4_cvt_kernel(const float* __restrict__ x,
                                 unsigned short* __restrict__ xb) {
  size_t t = (size_t)blockIdx.x * 256 + threadIdx.x;   // granule id
  int l  = (int)(t & 63);
  int r  = l & 31, cq = l >> 5;
  int sub = (int)(t >> 6) & 15;
  int mb = sub >> 2, ks = sub & 3;
  int H = (int)(t >> 10) & 63;
  int g = (int)(t >> 16);
  size_t row = (size_t)H * 128 + mb * 32 + r;
  size_t k   = (size_t)g * 64 + ks * 16 + cq * 8;
  const float* src = x + row * K_DIM + k;
  f32x4 v0 = *(const f32x4*)src;
  f32x4 v1 = *(const f32x4*)(src + 4);
  u16x8 out;
#pragma unroll
  for (int j = 0; j < 4; ++j) out[j]     = f2bf(v0[j]);
#pragma unroll
  for (int j = 0; j < 4; ++j) out[4 + j] = f2bf(v1[j]);
  *(u16x8*)(xb + t * 8) = out;
}

// ---------------- GEMM: A,B pre-blocked bf16, C [M,N] f32 + bias
// 256x256 tile, BK=64, 8 waves (2Mx4N), MFMA 32x32x16.
// NEW: B never touches LDS — each wave global_load_dwordx4's its 8 B frags
// (8 KB contiguous, fragment-ordered) into a register double-buffer, 1 tile
// ahead.  LDS holds only A (2 x 32 KB dbuf): reads drop 192->128 KB/K-tile,
// writes 64->32 KB. 2 phases + 2 barriers per K-tile, 16-MFMA clusters.
//   P1(g): gld B(g+1)->BN; stage A_HI(g+1); lgkm0[aLo]; 16 MFMA (mb01 x nb01);
//          ds_read aHi(g); BAR
//   P2(g): stage A_LO(g+2); lgkm0[aHi]; 16 MFMA (mb23 x nb01); vmcnt(2)
//          [publishes A(g+1)+B(g+1), keeps A_LO(g+2)]; BAR; ds_read aLo(g+1)
// Hazard proofs: A_LO(g+2) overwrites aLo(g) region - all waves drained aLo
// at P1's lgkm0, BAR at P1-end => safe.  A_HI(g+1) overwrites aHi(g-1) region
// - drained at P2(g-1) lgkm0, BAR at P2-end => safe.
// LDS elems: A buf b at b*16384 (h0 lo|hi, h1 lo|hi quadrants); dummy @32768.

#define BAR() __builtin_amdgcn_s_barrier()
#define WAIT_LGKM0() do { asm volatile("s_waitcnt lgkmcnt(0)" ::: "memory"); \
                          __builtin_amdgcn_sched_barrier(0); } while (0)

// lo-quadrants (subtiles 0-7) of both 128-row halves of tile t_ -> buf BUFA_
#define ST_A_LO(t_, BUFA_, valid_) do { \
  if (valid_) { \
    stage16(Abase + (size_t)(t_) * 524288 + tid8,        lp + (BUFA_) * 16384 + tid8); \
    stage16(Abase + (size_t)(t_) * 524288 + 8192 + tid8, lp + (BUFA_) * 16384 + 8192 + tid8); \
  } else { stage16(Abase + tid8, lp + 32768); \
           stage16(Abase + tid8, lp + 32768 + 512); } \
} while (0)

// hi-quadrants (subtiles 8-15) of both halves of tile t_ -> buf BUFA_
#define ST_A_HI(t_, BUFA_, valid_) do { \
  if (valid_) { \
    stage16(Abase + (size_t)(t_) * 524288 + 4096 + tid8,  lp + (BUFA_) * 16384 + 4096 + tid8); \
    stage16(Abase + (size_t)(t_) * 524288 + 12288 + tid8, lp + (BUFA_) * 16384 + 12288 + tid8); \
  } else { stage16(Abase + tid8, lp + 32768); \
           stage16(Abase + tid8, lp + 32768 + 512); } \
} while (0)

// 8x mfma_f32_32x32x16_bf16: m-blocks {MB_,MB_+1} x 1 n-block, 4 k-steps.
#define MF(MB_, NB_, AF_, BFP_) do { \
  _Pragma("unroll") \
  for (int ks_ = 0; ks_ < 4; ++ks_) \
    _Pragma("unroll") \
    for (int mm_ = 0; mm_ < 2; ++mm_) \
      acc[(MB_) + mm_][NB_] = __builtin_amdgcn_mfma_f32_32x32x16_bf16( \
          AF_[mm_][ks_], (BFP_)[ks_], acc[(MB_) + mm_][NB_], 0, 0, 0); \
} while (0)

// 8 ds_read_b128 of one mb-pair (HO_=0: mb01/aLo, HO_=8192: mb23/aHi) -> aF
#define RD_A(dsb_, HO_) do { \
  aF[0][0] = dsr<(HO_) + 0>(dsb_);    aF[0][1] = dsr<(HO_) + 1024>(dsb_); \
  aF[0][2] = dsr<(HO_) + 2048>(dsb_); aF[0][3] = dsr<(HO_) + 3072>(dsb_); \
  aF[1][0] = dsr<(HO_) + 4096>(dsb_); aF[1][1] = dsr<(HO_) + 5120>(dsb_); \
  aF[1][2] = dsr<(HO_) + 6144>(dsb_); aF[1][3] = dsr<(HO_) + 7168>(dsb_); \
} while (0)

// load wave's 8 B frags of tile t_ into regs R_ (8 KB contiguous, 2 bases)
#define GLD_B(R_, t_, valid_) do { \
  const unsigned short* pb_ = (valid_) ? (Bw + (size_t)(t_) * 262144) : Bw; \
  R_[0] = gld<0>(pb_);    R_[1] = gld<1024>(pb_); \
  R_[2] = gld<2048>(pb_); R_[3] = gld<3072>(pb_); \
  const unsigned short* pb2_ = pb_ + 2048; \
  R_[4] = gld<0>(pb2_);    R_[5] = gld<1024>(pb2_); \
  R_[6] = gld<2048>(pb2_); R_[7] = gld<3072>(pb2_); \
} while (0)

// One group = K-tile g. BUF_=g&1. BC_: B regs of tile g (landed). BN_: fill
// with B(tN_).  tN_=g+1 (B + A_HI), tL_=g+2 (A_LO).  On entry: aLo(g) ds_reads
// issued (lgkm=8), vm outstanding = A_LO(g+1) x2.
#define GROUP(BUF_, BC_, BN_, tN_, vN_, tL_, vL_, RDN_) do { \
  lds_us* dsA_  = lp + (BUF_) * 16384 + wm * 8192 + lane * 8; \
  lds_us* dsA2_ = lp + ((BUF_) ^ 1) * 16384 + wm * 8192 + lane * 8; \
  /* ---- P1: (mb0-1) x (nb0,nb1) ---- */ \
  GLD_B(BN_, tN_, vN_); \
  ST_A_HI(tN_, (BUF_) ^ 1, vN_); \
  WAIT_LGKM0(); /* aLo(g) landed */ \
  __builtin_amdgcn_s_setprio(1); \
  MF(0, 0, aF, BC_); MF(0, 1, aF, (BC_) + 4); \
  __builtin_amdgcn_s_setprio(0); \
  RD_A(dsA_, 8192);  /* issue aHi(g); completes under pipe drain */ \
  BAR(); \
  /* ---- P2: (mb2-3) x (nb0,nb1) ---- */ \
  ST_A_LO(tL_, (BUF_), vL_); \
  WAIT_LGKM0(); /* aHi(g) landed */ \
  __builtin_amdgcn_s_setprio(1); \
  MF(2, 0, aF, BC_); MF(2, 1, aF, (BC_) + 4); \
  __builtin_amdgcn_s_setprio(0); \
  asm volatile("s_waitcnt vmcnt(2)" ::: "memory"); /* A(g+1)+B(g+1) live */ \
  BAR(); \
  if (RDN_) { RD_A(dsA2_, 0); } /* issue aLo(g+1) */ \
} while (0)

__global__ __launch_bounds__(512, 2) void MXFP4_gemm_kernel(
    const unsigned short* __restrict__ A,
    const unsigned short* __restrict__ B,
    const float* __restrict__ bias,
    float* __restrict__ C) {
  __shared__ unsigned short LDS[33792];  // 66 KB: A dbuf 2x32KB + 2KB dummy
  lds_us* lp = (lds_us*)LDS;

  const int tid  = threadIdx.x;
  const int lane = tid & 63;
  const int wv   = tid >> 6;   // wave 0..7
  const int wm   = wv >> 2;    // 0..1  (M half: 128 rows)
  const int wn   = wv & 3;     // 0..3  (N quarter: 64 cols)
  const int tid8 = tid * 8;

  // 2-D chunk XCD swizzle: XCD x owns an 8tm x 8tn sub-square (bijective).
  const int bid = blockIdx.x;
  const int xcd = bid & 7;
  const int idx = bid >> 3;                 // 0..63 within XCD
  const int tm  = (xcd & 3) * 8 + (idx & 7);   // 0..31
  const int tn  = (xcd >> 2) * 8 + (idx >> 3); // 0..15
  const int brow = tm * 256;
  const int bcol = tn * 256;

  // A staging base (identity copy); B per-wave direct-load base:
  // wave's 8KB = H-block (tn*2 + wn>>1), col-block (wn&1), lane slot l*16B.
  const unsigned short* Abase = A + (size_t)(tm * 2) * 8192;
  const unsigned short* Bw =
      B + (size_t)(tn * 2 + (wn >> 1)) * 8192 + (wn & 1) * 4096 + lane * 8;

  f32x16 acc[4][2] = {};                 // (mb 0..3) x (nb 0..1), 32x32 each
  bf16x8 aF[2][4];                       // current mb-pair A frags
  bf16x8 b0[8], b1[8];                   // B frag double-buffer (tile parity)

  // ---- prologue: A(0) lo+hi, B(0)->b0, A(1) lo;  fence keeps A_LO(1) ----
  ST_A_LO(0, 0, true); ST_A_HI(0, 0, true);
  GLD_B(b0, 0, true);
  ST_A_LO(1, 1, true);
  asm volatile("s_waitcnt vmcnt(2)" ::: "memory");  // A(0)+B(0) landed
  BAR();
  { lds_us* dsA0 = lp + wm * 8192 + lane * 8;
    RD_A(dsA0, 0); }                               // issue aLo(0)

  // ---- main loop: g = 0..61 ----
  for (int it = 0; it < 31; ++it) {
    const int g0 = 2 * it;
    GROUP(0, b0, b1, g0 + 1, true, g0 + 2, true, true);
    GROUP(1, b1, b0, g0 + 2, true, g0 + 3, true, true);
  }
  // ---- tail: g = 62, 63 (dummy stages/loads keep fence accounting) ----
  GROUP(0, b0, b1, 63, true, 64, false, true);
  GROUP(1, b1, b0, 64, false, 65, false, false);

  // ---- epilogue: C = acc + bias ----
  // 32x32 C/D frag: col = lane&31, row = (reg&3) + 8*(reg>>2) + 4*(lane>>5)
  const int rb = brow + wm * 128 + 4 * (lane >> 5);
  const int cb = bcol + wn * 64 + (lane & 31);
#pragma unroll
  for (int nb = 0; nb < 2; ++nb) {
    const int col = cb + nb * 32;
    const float bv = bias[col];
#pragma unroll
    for (int mb = 0; mb < 4; ++mb) {
      const int rowb = rb + mb * 32;
#pragma unroll
      for (int rg = 0; rg < 16; ++rg) {
        const int row = rowb + (rg & 3) + 8 * (rg >> 2);
        C[(size_t)row * N_DIM + col] = acc[mb][nb][rg] + bv;
      }
    }
  }
}

extern "C" void kernel_launch(void* const* d_in, const int* in_sizes, int n_in,
                              void* d_out, int out_size, void* d_ws, size_t ws_size,
                              hipStream_t stream) {
  const float* x      = (const float*)d_in[0];
  const int*   wq     = (const int*)d_in[1];
  const float* scales = (const float*)d_in[2];
  const float* bias   = (const float*)d_in[3];
  float*       out    = (float*)d_out;

  unsigned short* wb = (unsigned short*)d_ws;                    // 33.5 MB blocked
  unsigned short* xb = wb + (size_t)N_DIM * K_DIM;               // 67 MB blocked

  MXFP4_dequant_kernel<<<(N_DIM * (long)K_DIM / 8) / 256, 256, 0, stream>>>(wq, scales, wb);
  MXFP4_cvt_kernel<<<(M_DIM * (long)K_DIM / 8) / 256, 256, 0, stream>>>(x, xb);

  MXFP4_gemm_kernel<<<512, 512, 0, stream>>>(xb, wb, bias, out);
}

// Round 11
// 321.524 us; speedup vs baseline: 1.0045x; 1.0045x over previous
//
#include <hip/hip_runtime.h>
#include <stdint.h>

#define M_DIM 8192
#define N_DIM 4096
#define K_DIM 4096
#define NBLK  (K_DIM / 32)

typedef __attribute__((ext_vector_type(4)))  float          f32x4;
typedef __attribute__((ext_vector_type(16))) float          f32x16;
typedef __attribute__((ext_vector_type(8)))  short          bf16x8;
typedef __attribute__((ext_vector_type(4)))  int            i32x4;
typedef __attribute__((ext_vector_type(8)))  unsigned short u16x8;
typedef __attribute__((address_space(3)))    unsigned short lds_us;

// round-to-nearest-even fp32 -> bf16 bits (finite values only)
__device__ __forceinline__ unsigned short f2bf(float f) {
  unsigned u = __builtin_bit_cast(unsigned, f);
  u += 0x7fffu + ((u >> 16) & 1u);
  return (unsigned short)(u >> 16);
}

__device__ __forceinline__ void stage16(const unsigned short* g, lds_us* l) {
  __builtin_amdgcn_global_load_lds(
      (const __attribute__((address_space(1))) void*)g,
      (__attribute__((address_space(3))) void*)l, 16, 0, 0);
}

// inline-asm ds_read_b128 with immediate byte offset
template <int OFF>
__device__ __forceinline__ bf16x8 dsr(lds_us* addr) {
  bf16x8 d;
  asm volatile("ds_read_b128 %0, %1 offset:%2" : "=v"(d) : "v"(addr), "n"(OFF));
  return d;
}

// inline-asm global_load_dwordx4 (direct-to-register B fragments)
template <int OFF>
__device__ __forceinline__ bf16x8 gld(const unsigned short* addr) {
  bf16x8 d;
  asm volatile("global_load_dwordx4 %0, %1, off offset:%2"
               : "=v"(d) : "v"(addr), "n"(OFF));
  return d;
}

// ============ BLOCKED GLOBAL LAYOUT for xb / wb (32x32x16 fragments) ======
// Granule = 16 B = one lane's frag slice. Block (g64, H) = 16 KB contiguous:
// 16 subtiles (mb 0..3 x ks 0..3) of 1 KB; granule slot == MFMA lane.
// Element (row,k): row = H*128 + mb*32 + (l&31); k = g64*64 + ks*16 + (l>>5)*8.
// (producers unchanged and verified since round 6)

__global__ void MXFP4_dequant_kernel(const int* __restrict__ wq,
                                     const float* __restrict__ scales,
                                     unsigned short* __restrict__ wb) {
  size_t t = (size_t)blockIdx.x * 256 + threadIdx.x;
  int l  = (int)(t & 63);
  int r  = l & 31, cq = l >> 5;
  int sub = (int)(t >> 6) & 15;
  int mb = sub >> 2, ks = sub & 3;
  int H = (int)(t >> 10) & 31;
  int g = (int)(t >> 15);
  size_t row = (size_t)H * 128 + mb * 32 + r;
  size_t k   = (size_t)g * 64 + ks * 16 + cq * 8;
  float s = scales[row * NBLK + (k >> 5)] * (1.0f / 7.0f);
  const int* src = wq + row * K_DIM + k;
  i32x4 q0 = *(const i32x4*)src;
  i32x4 q1 = *(const i32x4*)(src + 4);
  u16x8 out;
#pragma unroll
  for (int j = 0; j < 4; ++j) out[j]     = f2bf((float)q0[j] * s);
#pragma unroll
  for (int j = 0; j < 4; ++j) out[4 + j] = f2bf((float)q1[j] * s);
  *(u16x8*)(wb + t * 8) = out;
}

__global__ void MXFP4_cvt_kernel(const float* __restrict__ x,
                                 unsigned short* __restrict__ xb) {
  size_t t = (size_t)blockIdx.x * 256 + threadIdx.x;
  int l  = (int)(t & 63);
  int r  = l & 31, cq = l >> 5;
  int sub = (int)(t >> 6) & 15;
  int mb = sub >> 2, ks = sub & 3;
  int H = (int)(t >> 10) & 63;
  int g = (int)(t >> 16);
  size_t row = (size_t)H * 128 + mb * 32 + r;
  size_t k   = (size_t)g * 64 + ks * 16 + cq * 8;
  const float* src = x + row * K_DIM + k;
  f32x4 v0 = *(const f32x4*)src;
  f32x4 v1 = *(const f32x4*)(src + 4);
  u16x8 out;
#pragma unroll
  for (int j = 0; j < 4; ++j) out[j]     = f2bf(v0[j]);
#pragma unroll
  for (int j = 0; j < 4; ++j) out[4 + j] = f2bf(v1[j]);
  *(u16x8*)(xb + t * 8) = out;
}

// ---------------- GEMM: A,B pre-blocked bf16, C [M,N] f32 + bias
// 128x256 tile, BK=64, 4 waves, MFMA 32x32x16, **2 blocks/CU co-resident**
// (independent barrier domains overlap each other's drain windows).
// A: LDS dbuf 2x16KB (identity copy; all 4 waves broadcast-read the same
// subtiles). B: direct global->reg double-buffer (verified R9 scheme).
// Schedule per K-tile g (buffer BUF=g&1), exactly R9's verified 2-phase:
//   P1: gld B(g+1); stage A_HI(g+1)->BUF^1; lgkm0[aLo]; 16 MFMA (mb01xnb01);
//       issue aHi(g) ds_reads; BAR
//   P2: stage A_LO(g+2)->BUF; lgkm0[aHi]; 16 MFMA (mb23xnb01); vmcnt(2)
//       [drains A_LO(g+1)+B(g+1)+A_HI(g+1); keeps A_LO(g+2)]; BAR;
//       issue aLo(g+1) ds_reads from BUF^1
// LDS elems: BUF b at b*8192 (lo 0..4095 = mb01, hi 4096..8191 = mb23);
// dummy at 16384.

#define BAR() __builtin_amdgcn_s_barrier()
#define WAIT_LGKM0() do { asm volatile("s_waitcnt lgkmcnt(0)" ::: "memory"); \
                          __builtin_amdgcn_sched_barrier(0); } while (0)
#define PRIO1() __builtin_amdgcn_s_setprio(1)
#define PRIO0() __builtin_amdgcn_s_setprio(0)

// lo half (mb0,mb1; 4096 elems) of A K-tile t_ -> buf BUF_ (2 stages/thread)
#define ST_A_LO(t_, BUF_, valid_) do { \
  if (valid_) { \
    stage16(Abase + (size_t)(t_) * 524288 + tid8,        lp + (BUF_) * 8192 + tid8); \
    stage16(Abase + (size_t)(t_) * 524288 + 2048 + tid8, lp + (BUF_) * 8192 + 2048 + tid8); \
  } else { stage16(Abase + tid8, lp + 16384 + tid8); \
           stage16(Abase + tid8, lp + 16384 + tid8); } \
} while (0)

// hi half (mb2,mb3) of A K-tile t_ -> buf BUF_
#define ST_A_HI(t_, BUF_, valid_) do { \
  if (valid_) { \
    stage16(Abase + (size_t)(t_) * 524288 + 4096 + tid8, lp + (BUF_) * 8192 + 4096 + tid8); \
    stage16(Abase + (size_t)(t_) * 524288 + 6144 + tid8, lp + (BUF_) * 8192 + 6144 + tid8); \
  } else { stage16(Abase + tid8, lp + 16384 + tid8); \
           stage16(Abase + tid8, lp + 16384 + tid8); } \
} while (0)

// 8x mfma_f32_32x32x16_bf16: m-blocks {MB_,MB_+1} x 1 n-block, 4 k-steps.
#define MF(MB_, NB_, AF_, BFP_) do { \
  _Pragma("unroll") \
  for (int ks_ = 0; ks_ < 4; ++ks_) \
    _Pragma("unroll") \
    for (int mm_ = 0; mm_ < 2; ++mm_) \
      acc[(MB_) + mm_][NB_] = __builtin_amdgcn_mfma_f32_32x32x16_bf16( \
          AF_[mm_][ks_], (BFP_)[ks_], acc[(MB_) + mm_][NB_], 0, 0, 0); \
} while (0)

// 8 ds_read_b128 of one mb-pair (HO_=0: mb01, HO_=8192: mb23) -> aF
// (byte offsets; mb stride 4096 B = 4 subtiles, ks stride 1024 B)
#define RD_A(dsb_, HO_) do { \
  aF[0][0] = dsr<(HO_) + 0>(dsb_);    aF[0][1] = dsr<(HO_) + 1024>(dsb_); \
  aF[0][2] = dsr<(HO_) + 2048>(dsb_); aF[0][3] = dsr<(HO_) + 3072>(dsb_); \
  aF[1][0] = dsr<(HO_) + 4096>(dsb_); aF[1][1] = dsr<(HO_) + 5120>(dsb_); \
  aF[1][2] = dsr<(HO_) + 6144>(dsb_); aF[1][3] = dsr<(HO_) + 7168>(dsb_); \
} while (0)

// load wave's 8 B frags of tile t_ into regs R_ (8 KB contiguous, 2 mb bases)
#define GLD_B(R_, t_, valid_) do { \
  const unsigned short* pb_ = (valid_) ? (Bw + (size_t)(t_) * 262144) : Bw; \
  R_[0] = gld<0>(pb_);    R_[1] = gld<1024>(pb_); \
  R_[2] = gld<2048>(pb_); R_[3] = gld<3072>(pb_); \
  const unsigned short* pb2_ = pb_ + 2048; \
  R_[4] = gld<0>(pb2_);    R_[5] = gld<1024>(pb2_); \
  R_[6] = gld<2048>(pb2_); R_[7] = gld<3072>(pb2_); \
} while (0)

// One group = K-tile g. BUF_=g&1. BC_: B regs of tile g (landed). BN_: fill
// with B(tN_=g+1). tL_=g+2 (A_LO). On entry: aLo(g) ds_reads issued,
// vm outstanding = A_LO(g+1) x2.
#define GROUP(BUF_, BC_, BN_, tN_, vN_, tL_, vL_, RDN_) do { \
  lds_us* dsA_  = lp + (BUF_) * 8192 + lane * 8; \
  lds_us* dsA2_ = lp + ((BUF_) ^ 1) * 8192 + lane * 8; \
  /* ---- P1: (mb0-1) x (nb0,nb1) ---- */ \
  GLD_B(BN_, tN_, vN_); \
  ST_A_HI(tN_, (BUF_) ^ 1, vN_); \
  WAIT_LGKM0(); /* aLo(g) landed */ \
  PRIO1(); \
  MF(0, 0, aF, BC_); MF(0, 1, aF, (BC_) + 4); \
  PRIO0(); \
  RD_A(dsA_, 8192);  /* issue aHi(g) */ \
  BAR(); \
  /* ---- P2: (mb2-3) x (nb0,nb1) ---- */ \
  ST_A_LO(tL_, (BUF_), vL_); \
  WAIT_LGKM0(); /* aHi(g) landed */ \
  PRIO1(); \
  MF(2, 0, aF, BC_); MF(2, 1, aF, (BC_) + 4); \
  PRIO0(); \
  asm volatile("s_waitcnt vmcnt(2)" ::: "memory"); /* A(g+1)+B(g+1) live */ \
  BAR(); \
  if (RDN_) { RD_A(dsA2_, 0); } /* issue aLo(g+1) */ \
} while (0)

__global__ __launch_bounds__(256, 2) void MXFP4_gemm_kernel(
    const unsigned short* __restrict__ A,
    const unsigned short* __restrict__ B,
    const float* __restrict__ bias,
    float* __restrict__ C) {
  __shared__ unsigned short LDS[18432];  // 36 KB: A dbuf 2x16KB + 4KB dummy
  lds_us* lp = (lds_us*)LDS;

  const int tid  = threadIdx.x;
  const int lane = tid & 63;
  const int wn   = tid >> 6;   // wave 0..3 (N quarter: 64 cols)
  const int tid8 = tid * 8;

  // 2-D chunk XCD swizzle: XCD x owns a 16tm x 8tn sub-rectangle (bijective,
  // 1024 blocks). Per-XCD footprint: A 16 MB + B 16 MB.
  const int bid = blockIdx.x;
  const int xcd = bid & 7;
  const int idx = bid >> 3;                    // 0..127 within XCD
  const int tm  = (xcd & 3) * 16 + (idx & 15); // 0..63
  const int tn  = (xcd >> 2) * 8 + (idx >> 4); // 0..15
  const int brow = tm * 128;
  const int bcol = tn * 256;

  // A staging base (tile = one H-block; K-tile stride 524288 elems);
  // B per-wave direct-load base (identical formula to verified R9).
  const unsigned short* Abase = A + (size_t)tm * 8192;
  const unsigned short* Bw =
      B + (size_t)(tn * 2 + (wn >> 1)) * 8192 + (wn & 1) * 4096 + lane * 8;

  f32x16 acc[4][2] = {};                 // (mb 0..3) x (nb 0..1), 32x32 each
  bf16x8 aF[2][4];                       // current mb-pair A frags
  bf16x8 b0[8], b1[8];                   // B frag double-buffer (tile parity)

  // ---- prologue: A(0) lo+hi, B(0)->b0, A(1) lo; fence keeps A_LO(1) ----
  ST_A_LO(0, 0, true); ST_A_HI(0, 0, true);
  GLD_B(b0, 0, true);
  ST_A_LO(1, 1, true);
  asm volatile("s_waitcnt vmcnt(2)" ::: "memory");  // A(0)+B(0) landed
  BAR();
  { lds_us* dsA0 = lp + lane * 8;
    RD_A(dsA0, 0); }                               // issue aLo(0)

  // ---- main loop: g = 0..61 ----
  for (int it = 0; it < 31; ++it) {
    const int g0 = 2 * it;
    GROUP(0, b0, b1, g0 + 1, true, g0 + 2, true, true);
    GROUP(1, b1, b0, g0 + 2, true, g0 + 3, true, true);
  }
  // ---- tail: g = 62, 63 (dummy stages/loads keep fence accounting) ----
  GROUP(0, b0, b1, 63, true, 64, false, true);
  GROUP(1, b1, b0, 64, false, 65, false, false);

  // ---- epilogue: C = acc + bias ----
  // 32x32 C/D frag: col = lane&31, row = (reg&3) + 8*(reg>>2) + 4*(lane>>5)
  const int rb = brow + 4 * (lane >> 5);
  const int cb = bcol + wn * 64 + (lane & 31);
#pragma unroll
  for (int nb = 0; nb < 2; ++nb) {
    const int col = cb + nb * 32;
    const float bv = bias[col];
#pragma unroll
    for (int mb = 0; mb < 4; ++mb) {
      const int rowb = rb + mb * 32;
#pragma unroll
      for (int rg = 0; rg < 16; ++rg) {
        const int row = rowb + (rg & 3) + 8 * (rg >> 2);
        C[(size_t)row * N_DIM + col] = acc[mb][nb][rg] + bv;
      }
    }
  }
}

extern "C" void kernel_launch(void* const* d_in, const int* in_sizes, int n_in,
                              void* d_out, int out_size, void* d_ws, size_t ws_size,
                              hipStream_t stream) {
  const float* x      = (const float*)d_in[0];
  const int*   wq     = (const int*)d_in[1];
  const float* scales = (const float*)d_in[2];
  const float* bias   = (const float*)d_in[3];
  float*       out    = (float*)d_out;

  unsigned short* wb = (unsigned short*)d_ws;                    // 33.5 MB blocked
  unsigned short* xb = wb + (size_t)N_DIM * K_DIM;               // 67 MB blocked

  MXFP4_dequant_kernel<<<(N_DIM * (long)K_DIM / 8) / 256, 256, 0, stream>>>(wq, scales, wb);
  MXFP4_cvt_kernel<<<(M_DIM * (long)K_DIM / 8) / 256, 256, 0, stream>>>(x, xb);

  MXFP4_gemm_kernel<<<1024, 256, 0, stream>>>(xb, wb, bias, out);
}